// Round 1
// baseline (2295.779 us; speedup 1.0000x reference)
//
#include <hip/hip_runtime.h>

constexpr int BATCH = 2048;
constexpr int SEQ   = 512;
constexpr int H     = 50;
constexpr int G4    = 200;   // 4*H gate outputs
constexpr int KP    = 52;    // padded row length (13 float4s)
constexpr int MB    = 8;     // batch elements per block
constexpr int NT    = 512;   // threads per block (8 waves, 2/SIMD)

__device__ __forceinline__ float sigm(float x) {
    return 1.0f / (1.0f + __expf(-x));
}
__device__ __forceinline__ float tanh_fast(float x) {
    // stable: a = exp(-2|x|) in (0,1], t = (1-a)/(1+a), sign restored
    float a = __expf(-2.0f * fabsf(x));
    float t = (1.0f - a) / (1.0f + a);
    return copysignf(t, x);
}

__global__ __launch_bounds__(NT, 2) void lstm2_fused(
    const float* __restrict__ x,
    const float* __restrict__ Wih0, const float* __restrict__ Whh0,
    const float* __restrict__ bih0, const float* __restrict__ bhh0,
    const float* __restrict__ Wih1, const float* __restrict__ Whh1,
    const float* __restrict__ bih1, const float* __restrict__ bhh1,
    const float* __restrict__ fcW,  const float* __restrict__ fcb,
    float* __restrict__ out)
{
    __shared__ float sWhh0[G4 * KP];   // 41.6 KB
    __shared__ float sWih1[G4 * KP];   // 41.6 KB
    __shared__ float sWhh1[G4 * KP];   // 41.6 KB
    __shared__ float sH0[MB * KP];     // layer0 h state (= layer1 input)
    __shared__ float sH2[MB * KP];     // layer1 h state
    __shared__ float sG[MB * G4];      // gate preactivations (reused L0/L1)
    __shared__ float sX[MB * 64];      // staged x chunk (64 steps)

    const int tid   = threadIdx.x;
    const int bbase = blockIdx.x * MB;

    // ---- stage weights into LDS (rows padded 50 -> 52 with zeros) ----
    for (int i = tid; i < G4 * H; i += NT) {
        int r = i / H, c = i - r * H;
        sWhh0[r * KP + c] = Whh0[i];
        sWih1[r * KP + c] = Wih1[i];
        sWhh1[r * KP + c] = Whh1[i];
    }
    for (int r = tid; r < G4; r += NT) {
        sWhh0[r * KP + 50] = 0.f; sWhh0[r * KP + 51] = 0.f;
        sWih1[r * KP + 50] = 0.f; sWih1[r * KP + 51] = 0.f;
        sWhh1[r * KP + 50] = 0.f; sWhh1[r * KP + 51] = 0.f;
    }
    for (int i = tid; i < MB * KP; i += NT) { sH0[i] = 0.f; sH2[i] = 0.f; }

    // ---- per-thread constants ----
    const int n  = tid % G4;     // gate-output index (matmul phases, tid<400)
    const int bq = tid / G4;     // batch quad (0/1)
    const int cb = tid / H;      // batch index (combine phases, tid<400)
    const int cj = tid - cb * H; // hidden index
    float wx0 = 0.f, bias0 = 0.f, bias1 = 0.f;
    if (tid < 2 * G4) {
        wx0   = Wih0[n];               // INPUT_SIZE == 1
        bias0 = bih0[n] + bhh0[n];
        bias1 = bih1[n] + bhh1[n];
    }
    float c0 = 0.f, c1 = 0.f;          // cell states live in registers

    __syncthreads();

    #pragma unroll 1
    for (int s = 0; s < SEQ; ++s) {
        // ---- stage next 64 timesteps of x, coalesced ----
        if ((s & 63) == 0) {
            for (int i = tid; i < MB * 64; i += NT) {
                int b = i >> 6, ss = i & 63;
                sX[i] = x[(bbase + b) * SEQ + s + ss];
            }
            __syncthreads();
        }

        // ---- Phase A: layer0 gate preacts: g = x*wih0 + b0 + Whh0 . h0 ----
        if (tid < 2 * G4) {
            const float4* wr = (const float4*)&sWhh0[n * KP];
            float acc[4];
            #pragma unroll
            for (int m = 0; m < 4; ++m)
                acc[m] = wx0 * sX[(bq * 4 + m) * 64 + (s & 63)] + bias0;
            #pragma unroll
            for (int kc = 0; kc < KP / 4; ++kc) {
                float4 w = wr[kc];
                #pragma unroll
                for (int m = 0; m < 4; ++m) {
                    float4 h = *(const float4*)&sH0[(bq * 4 + m) * KP + kc * 4];
                    acc[m] += w.x * h.x; acc[m] += w.y * h.y;
                    acc[m] += w.z * h.z; acc[m] += w.w * h.w;
                }
            }
            #pragma unroll
            for (int m = 0; m < 4; ++m)
                sG[(bq * 4 + m) * G4 + n] = acc[m];
        }
        __syncthreads();

        // ---- Phase B: layer0 combine -> c0 (regs), h0 -> LDS ----
        if (tid < MB * H) {
            float gi = sG[cb * G4 + cj];
            float gf = sG[cb * G4 + 50 + cj];
            float gg = sG[cb * G4 + 100 + cj];
            float go = sG[cb * G4 + 150 + cj];
            c0 = sigm(gf) * c0 + sigm(gi) * tanh_fast(gg);
            sH0[cb * KP + cj] = sigm(go) * tanh_fast(c0);
        }
        __syncthreads();

        // ---- Phase C: layer1 gate preacts: g = b1 + Wih1 . h1_t + Whh1 . h2 ----
        if (tid < 2 * G4) {
            const float4* w1r = (const float4*)&sWih1[n * KP];
            const float4* w2r = (const float4*)&sWhh1[n * KP];
            float acc[4];
            #pragma unroll
            for (int m = 0; m < 4; ++m) acc[m] = bias1;
            #pragma unroll
            for (int kc = 0; kc < KP / 4; ++kc) {
                float4 w1 = w1r[kc];
                float4 w2 = w2r[kc];
                #pragma unroll
                for (int m = 0; m < 4; ++m) {
                    float4 ha = *(const float4*)&sH0[(bq * 4 + m) * KP + kc * 4];
                    float4 hb = *(const float4*)&sH2[(bq * 4 + m) * KP + kc * 4];
                    acc[m] += w1.x * ha.x; acc[m] += w1.y * ha.y;
                    acc[m] += w1.z * ha.z; acc[m] += w1.w * ha.w;
                    acc[m] += w2.x * hb.x; acc[m] += w2.y * hb.y;
                    acc[m] += w2.z * hb.z; acc[m] += w2.w * hb.w;
                }
            }
            #pragma unroll
            for (int m = 0; m < 4; ++m)
                sG[(bq * 4 + m) * G4 + n] = acc[m];
        }
        __syncthreads();

        // ---- Phase D: layer1 combine -> c1 (regs), h2 -> LDS ----
        if (tid < MB * H) {
            float gi = sG[cb * G4 + cj];
            float gf = sG[cb * G4 + 50 + cj];
            float gg = sG[cb * G4 + 100 + cj];
            float go = sG[cb * G4 + 150 + cj];
            c1 = sigm(gf) * c1 + sigm(gi) * tanh_fast(gg);
            sH2[cb * KP + cj] = sigm(go) * tanh_fast(c1);
        }
        __syncthreads();
    }

    // ---- FC epilogue: out[b] = fcW . h2_last[b] + fcb ----
    if (tid < MB * H) {
        sG[cb * H + cj] = sH2[cb * KP + cj] * fcW[cj];
    }
    __syncthreads();
    if (tid < MB) {
        float sum = fcb[0];
        #pragma unroll
        for (int j = 0; j < H; ++j) sum += sG[tid * H + j];
        out[bbase + tid] = sum;
    }
}

extern "C" void kernel_launch(void* const* d_in, const int* in_sizes, int n_in,
                              void* d_out, int out_size, void* d_ws, size_t ws_size,
                              hipStream_t stream)
{
    const float* x    = (const float*)d_in[0];
    const float* Wih0 = (const float*)d_in[1];
    const float* Whh0 = (const float*)d_in[2];
    const float* bih0 = (const float*)d_in[3];
    const float* bhh0 = (const float*)d_in[4];
    const float* Wih1 = (const float*)d_in[5];
    const float* Whh1 = (const float*)d_in[6];
    const float* bih1 = (const float*)d_in[7];
    const float* bhh1 = (const float*)d_in[8];
    const float* fcW  = (const float*)d_in[9];
    const float* fcb  = (const float*)d_in[10];

    lstm2_fused<<<BATCH / MB, NT, 0, stream>>>(
        x, Wih0, Whh0, bih0, bhh0, Wih1, Whh1, bih1, bhh1, fcW, fcb,
        (float*)d_out);
}

// Round 2
// 1775.270 us; speedup vs baseline: 1.2932x; 1.2932x over previous
//
#include <hip/hip_runtime.h>

constexpr int BATCH = 2048;
constexpr int SEQ   = 512;
constexpr int H     = 50;
constexpr int G4    = 200;   // 4*H gate rows
constexpr int NB    = 4;     // batch elements per block
constexpr int NT    = 256;   // threads per block (4 waves)
constexpr int HP    = 52;    // padded h length (13 float4s)

__device__ __forceinline__ float sigm(float x) {
    return 1.0f / (1.0f + __expf(-x));
}
__device__ __forceinline__ float tanh_fast(float x) {
    float a = __expf(-2.0f * fabsf(x));
    float t = (1.0f - a) / (1.0f + a);
    return copysignf(t, x);
}

__global__ __launch_bounds__(NT, 2) void lstm2_regw(
    const float* __restrict__ x,
    const float* __restrict__ Wih0, const float* __restrict__ Whh0,
    const float* __restrict__ bih0, const float* __restrict__ bhh0,
    const float* __restrict__ Wih1, const float* __restrict__ Whh1,
    const float* __restrict__ bih1, const float* __restrict__ bhh1,
    const float* __restrict__ fcW,  const float* __restrict__ fcb,
    float* __restrict__ out)
{
    __shared__ float sH0[NB * HP];   // layer0 h (= layer1 input), padded
    __shared__ float sH2[NB * HP];   // layer1 h, padded
    __shared__ float sG[NB * 256];   // gate preacts (256-padded rows)
    __shared__ float sX[NB * 64];    // staged x chunk (64 steps)

    const int tid   = threadIdx.x;
    const int bbase = blockIdx.x * NB;

    // zero h state (and pads)
    for (int i = tid; i < NB * HP; i += NT) { sH0[i] = 0.f; sH2[i] = 0.f; }

    // ---- weights into REGISTERS: thread tid owns gate row n = tid ----
    const int   n   = tid;
    const int   nc  = (n < G4) ? n : 0;     // clamp to avoid OOB
    const float msk = (n < G4) ? 1.f : 0.f; // zero-mask fake rows
    float w0[HP], wi1[HP], wh1[HP];
    #pragma unroll
    for (int k = 0; k < H; ++k) {
        w0 [k] = Whh0[nc * H + k] * msk;
        wi1[k] = Wih1[nc * H + k] * msk;
        wh1[k] = Whh1[nc * H + k] * msk;
    }
    #pragma unroll
    for (int k = H; k < HP; ++k) { w0[k] = 0.f; wi1[k] = 0.f; wh1[k] = 0.f; }
    const float wx0   = Wih0[nc] * msk;            // INPUT_SIZE == 1
    const float bias0 = (bih0[nc] + bhh0[nc]) * msk;
    const float bias1 = (bih1[nc] + bhh1[nc]) * msk;

    // combine-phase mapping (threads 0..199): (batch cb, hidden cj)
    const int cb = tid / H;
    const int cj = tid - cb * H;
    float c0 = 0.f, c1 = 0.f;                      // cell states in registers

    __syncthreads();

    #pragma unroll 1
    for (int s = 0; s < SEQ; ++s) {
        // ---- stage next 64 timesteps of x (coalesced, once per 64 steps) ----
        if ((s & 63) == 0) {
            const int b = tid >> 6, st = tid & 63;
            sX[tid] = x[(bbase + b) * SEQ + s + st];
            __syncthreads();
        }
        const int ss = s & 63;

        // ---- Phase A: layer0 gates: g = wx0*x_t + b0 + Whh0[n,:].h0 ----
        float acc[NB];
        #pragma unroll
        for (int b = 0; b < NB; ++b)
            acc[b] = fmaf(wx0, sX[b * 64 + ss], bias0);
        #pragma unroll
        for (int kc = 0; kc < HP / 4; ++kc) {
            #pragma unroll
            for (int b = 0; b < NB; ++b) {
                float4 h = *(const float4*)&sH0[b * HP + kc * 4];
                acc[b] = fmaf(w0[kc * 4 + 0], h.x, acc[b]);
                acc[b] = fmaf(w0[kc * 4 + 1], h.y, acc[b]);
                acc[b] = fmaf(w0[kc * 4 + 2], h.z, acc[b]);
                acc[b] = fmaf(w0[kc * 4 + 3], h.w, acc[b]);
            }
        }
        #pragma unroll
        for (int b = 0; b < NB; ++b) sG[b * 256 + n] = acc[b];
        __syncthreads();

        // ---- Phase B: layer0 combine -> c0 (regs), h0 -> LDS ----
        if (tid < NB * H) {
            float gi = sG[cb * 256 +       cj];
            float gf = sG[cb * 256 +  50 + cj];
            float gg = sG[cb * 256 + 100 + cj];
            float go = sG[cb * 256 + 150 + cj];
            c0 = sigm(gf) * c0 + sigm(gi) * tanh_fast(gg);
            sH0[cb * HP + cj] = sigm(go) * tanh_fast(c0);
        }
        __syncthreads();

        // ---- Phase C: layer1 gates: g = b1 + Wih1[n,:].h1_t + Whh1[n,:].h2 ----
        #pragma unroll
        for (int b = 0; b < NB; ++b) acc[b] = bias1;
        #pragma unroll
        for (int kc = 0; kc < HP / 4; ++kc) {
            #pragma unroll
            for (int b = 0; b < NB; ++b) {
                float4 ha = *(const float4*)&sH0[b * HP + kc * 4];
                float4 hb = *(const float4*)&sH2[b * HP + kc * 4];
                acc[b] = fmaf(wi1[kc * 4 + 0], ha.x, acc[b]);
                acc[b] = fmaf(wi1[kc * 4 + 1], ha.y, acc[b]);
                acc[b] = fmaf(wi1[kc * 4 + 2], ha.z, acc[b]);
                acc[b] = fmaf(wi1[kc * 4 + 3], ha.w, acc[b]);
                acc[b] = fmaf(wh1[kc * 4 + 0], hb.x, acc[b]);
                acc[b] = fmaf(wh1[kc * 4 + 1], hb.y, acc[b]);
                acc[b] = fmaf(wh1[kc * 4 + 2], hb.z, acc[b]);
                acc[b] = fmaf(wh1[kc * 4 + 3], hb.w, acc[b]);
            }
        }
        #pragma unroll
        for (int b = 0; b < NB; ++b) sG[b * 256 + n] = acc[b];
        __syncthreads();

        // ---- Phase D: layer1 combine -> c1 (regs), h2 -> LDS ----
        if (tid < NB * H) {
            float gi = sG[cb * 256 +       cj];
            float gf = sG[cb * 256 +  50 + cj];
            float gg = sG[cb * 256 + 100 + cj];
            float go = sG[cb * 256 + 150 + cj];
            c1 = sigm(gf) * c1 + sigm(gi) * tanh_fast(gg);
            sH2[cb * HP + cj] = sigm(go) * tanh_fast(c1);
        }
        __syncthreads();
    }

    // ---- FC epilogue: out[b] = fcW . h2_last[b] + fcb ----
    if (tid < NB * H) sG[cb * H + cj] = sH2[cb * HP + cj] * fcW[cj];
    __syncthreads();
    if (tid < NB) {
        float sum = fcb[0];
        #pragma unroll
        for (int j = 0; j < H; ++j) sum += sG[tid * H + j];
        out[bbase + tid] = sum;
    }
}

extern "C" void kernel_launch(void* const* d_in, const int* in_sizes, int n_in,
                              void* d_out, int out_size, void* d_ws, size_t ws_size,
                              hipStream_t stream)
{
    const float* x    = (const float*)d_in[0];
    const float* Wih0 = (const float*)d_in[1];
    const float* Whh0 = (const float*)d_in[2];
    const float* bih0 = (const float*)d_in[3];
    const float* bhh0 = (const float*)d_in[4];
    const float* Wih1 = (const float*)d_in[5];
    const float* Whh1 = (const float*)d_in[6];
    const float* bih1 = (const float*)d_in[7];
    const float* bhh1 = (const float*)d_in[8];
    const float* fcW  = (const float*)d_in[9];
    const float* fcb  = (const float*)d_in[10];

    lstm2_regw<<<BATCH / NB, NT, 0, stream>>>(
        x, Wih0, Whh0, bih0, bhh0, Wih1, Whh1, bih1, bhh1, fcW, fcb,
        (float*)d_out);
}